// Round 4
// baseline (206.100 us; speedup 1.0000x reference)
//
#include <hip/hip_runtime.h>

// AWGN index channel: rx = idx XOR bitflip-mask(u < BER), codebook gather,
// concat [fine | coarse] per batch row. Exact integer semantics -> absmax 0.
//
// R7: DISCRIMINATING PROBE, not an optimization. Three structurally distinct
// kernels (R3/R5/R6) all measure ~183-185us clock-normalized. Timed region =
// ~100us poison fill + ~83us unexplained. Fork:
//   H1: our kernel is ~83us (2.1 TB/s on a 168MB write stream, mechanism
//       unknown -- every candidate mechanism falsified so far).
//   H2: our kernel is ~30-40us (write roofline) and ~50us is the harness's
//       hidden tiny restore dispatches inside the timed window.
// Probe: run the gather/store phase TWICE (idempotent; asm memory clobber
// prevents load-merging/dead-store-elim between passes).
//   H1 -> dur_us ~255-265 and our kernel (~160us) ENTERS top-5 with real
//         counters (hbm_gbps of the store stream becomes visible).
//   H2 -> dur_us ~205-220, kernel stays hidden -> controllable part is at
//         roofline; declare <<ROOFLINE>> next round.

typedef float f4 __attribute__((ext_vector_type(4)));

constexpr int   BITS       = 9;
constexpr float BER        = 0.02f;
constexpr int   Bn         = 64;
constexpr int   HC = 32, WC = 32, HF = 64, WF = 64, D = 128;
constexpr int   NF         = Bn * HF * WF;     // 262144 fine symbols
constexpr int   NC         = Bn * HC * WC;     // 65536 coarse symbols
constexpr int   NTOT       = NF + NC;          // 327680
constexpr int   FINE_ROW   = HF * WF * D;      // 524288 floats
constexpr int   COARSE_ROW = HC * WC * D;      // 131072 floats
constexpr int   ROW        = FINE_ROW + COARSE_ROW; // 655360 floats / batch row

constexpr int   GRID  = 2048;                  // 8 blocks/CU
constexpr int   SPB   = NTOT / GRID;           // 160 symbols per block, exact
constexpr int   ITERS = SPB / 8;               // 20 store iterations

__global__ __launch_bounds__(256) void fused_kernel(
    const int*   __restrict__ idx_c,
    const int*   __restrict__ idx_f,
    const float* __restrict__ cb_c,
    const float* __restrict__ cb_f,
    const float* __restrict__ u_c,
    const float* __restrict__ u_f,
    float*       __restrict__ out)
{
    __shared__ int srow[SPB];                   // 640 B

    const int t  = threadIdx.x;
    const int s0 = blockIdx.x * SPB;            // first symbol of this block

    // ---- Phase 1: bit-flip channel for this block's 160 symbols -> LDS ----
    if (t < SPB) {
        const int i = s0 + t;
        const float* up;  const int* idxp;  int local;
        if (i < NF) { local = i;      up = u_f + (size_t)local * BITS; idxp = idx_f; }
        else        { local = i - NF; up = u_c + (size_t)local * BITS; idxp = idx_c; }
        int flip = 0;
        #pragma unroll
        for (int k = 0; k < BITS; ++k)
            flip |= (up[k] < BER) ? (1 << k) : 0;
        srow[t] = (idxp[local] ^ flip) & 511;   // clip is a no-op
    }
    __syncthreads();

    // ---- Phase 2: codebook gather + concat store (RUN TWICE: probe) ----
    const int sym  = t >> 5;                    // 0..7
    const int lane = t & 31;                    // float4 slot in 128-f row

    int row[ITERS];
    #pragma unroll
    for (int k = 0; k < ITERS; ++k)
        row[k] = srow[k * 8 + sym];             // broadcast LDS read

    // PASS A
    #pragma unroll 4
    for (int it = 0; it < ITERS; ++it) {
        const int i = s0 + it * 8 + sym;        // half-wave-uniform
        const float* src;  int off;
        if (i < NF) {
            const int b = i >> 12, rem = i & 4095;   // / , % (HF*WF)
            src = cb_f + row[it] * D;
            off = b * ROW + rem * D;
        } else {
            const int j = i - NF;
            const int b = j >> 10, rem = j & 1023;   // / , % (HC*WC)
            src = cb_c + row[it] * D;
            off = b * ROW + FINE_ROW + rem * D;
        }
        const f4 v = ((const f4*)src)[lane];
        ((f4*)(out + off))[lane] = v;
    }

    // Compiler may not merge the passes: asm may read/write any memory.
    asm volatile("" ::: "memory");

    // PASS B (identical, idempotent)
    #pragma unroll 4
    for (int it = 0; it < ITERS; ++it) {
        const int i = s0 + it * 8 + sym;
        const float* src;  int off;
        if (i < NF) {
            const int b = i >> 12, rem = i & 4095;
            src = cb_f + row[it] * D;
            off = b * ROW + rem * D;
        } else {
            const int j = i - NF;
            const int b = j >> 10, rem = j & 1023;
            src = cb_c + row[it] * D;
            off = b * ROW + FINE_ROW + rem * D;
        }
        const f4 v = ((const f4*)src)[lane];
        ((f4*)(out + off))[lane] = v;
    }
}

extern "C" void kernel_launch(void* const* d_in, const int* in_sizes, int n_in,
                              void* d_out, int out_size, void* d_ws, size_t ws_size,
                              hipStream_t stream) {
    const int*   idx_c = (const int*)  d_in[0];
    const int*   idx_f = (const int*)  d_in[1];
    const float* cb_c  = (const float*)d_in[2];
    const float* cb_f  = (const float*)d_in[3];
    const float* u_c   = (const float*)d_in[4];
    const float* u_f   = (const float*)d_in[5];
    float*       out   = (float*)d_out;
    (void)d_ws; (void)ws_size;

    fused_kernel<<<GRID, 256, 0, stream>>>(idx_c, idx_f, cb_c, cb_f, u_c, u_f, out);
}

// Round 5
// 183.846 us; speedup vs baseline: 1.1210x; 1.1210x over previous
//
#include <hip/hip_runtime.h>

// AWGN index channel: rx = idx XOR bitflip-mask(u < BER), codebook gather,
// concat [fine | coarse] per batch row. Exact integer semantics -> absmax 0.
//
// R8: revert R7's diagnostic double-pass; this is R6, the best verified
// kernel (183.5us). R7's probe settled the session's open question:
//   duplicate gather+store pass costs +22.6us -> single pass <= ~27-30us,
//   i.e. AT the 168MB/6.3TB/s write roofline. The other ~150us of the timed
//   window is harness-fixed (~100us poison fill + ~50us tiny restore
//   dispatches). No controllable time remains beyond a few percent.
// Structure: single fused kernel; block b owns symbols [160b, 160b+160).
//   Phase 1: threads 0..159 compute rx inline (9 contiguous u floats each,
//            5.76 KB/block coalesced) -> LDS. No global rx traffic.
//   Phase 2: half-wave (32 lanes x float4) per symbol gather from the
//            L2-resident codebooks; 4 KB contiguous store per iteration,
//            80 KB sequential per block.

typedef float f4 __attribute__((ext_vector_type(4)));

constexpr int   BITS       = 9;
constexpr float BER        = 0.02f;
constexpr int   Bn         = 64;
constexpr int   HC = 32, WC = 32, HF = 64, WF = 64, D = 128;
constexpr int   NF         = Bn * HF * WF;     // 262144 fine symbols
constexpr int   NC         = Bn * HC * WC;     // 65536 coarse symbols
constexpr int   NTOT       = NF + NC;          // 327680
constexpr int   FINE_ROW   = HF * WF * D;      // 524288 floats
constexpr int   COARSE_ROW = HC * WC * D;      // 131072 floats
constexpr int   ROW        = FINE_ROW + COARSE_ROW; // 655360 floats / batch row

constexpr int   GRID  = 2048;                  // 8 blocks/CU
constexpr int   SPB   = NTOT / GRID;           // 160 symbols per block, exact
constexpr int   ITERS = SPB / 8;               // 20 store iterations

__global__ __launch_bounds__(256) void fused_kernel(
    const int*   __restrict__ idx_c,
    const int*   __restrict__ idx_f,
    const float* __restrict__ cb_c,
    const float* __restrict__ cb_f,
    const float* __restrict__ u_c,
    const float* __restrict__ u_f,
    float*       __restrict__ out)
{
    __shared__ int srow[SPB];                   // 640 B

    const int t  = threadIdx.x;
    const int s0 = blockIdx.x * SPB;            // first symbol of this block

    // ---- Phase 1: bit-flip channel for this block's 160 symbols -> LDS ----
    if (t < SPB) {
        const int i = s0 + t;
        const float* up;  const int* idxp;  int local;
        if (i < NF) { local = i;      up = u_f + (size_t)local * BITS; idxp = idx_f; }
        else        { local = i - NF; up = u_c + (size_t)local * BITS; idxp = idx_c; }
        int flip = 0;
        #pragma unroll
        for (int k = 0; k < BITS; ++k)
            flip |= (up[k] < BER) ? (1 << k) : 0;
        srow[t] = (idxp[local] ^ flip) & 511;   // clip is a no-op
    }
    __syncthreads();

    // ---- Phase 2: codebook gather + concat store ----
    const int sym  = t >> 5;                    // 0..7
    const int lane = t & 31;                    // float4 slot in 128-f row

    int row[ITERS];
    #pragma unroll
    for (int k = 0; k < ITERS; ++k)
        row[k] = srow[k * 8 + sym];             // broadcast LDS read

    #pragma unroll 4
    for (int it = 0; it < ITERS; ++it) {
        const int i = s0 + it * 8 + sym;        // half-wave-uniform
        const float* src;  int off;
        if (i < NF) {
            const int b = i >> 12, rem = i & 4095;   // / , % (HF*WF)
            src = cb_f + row[it] * D;
            off = b * ROW + rem * D;
        } else {
            const int j = i - NF;
            const int b = j >> 10, rem = j & 1023;   // / , % (HC*WC)
            src = cb_c + row[it] * D;
            off = b * ROW + FINE_ROW + rem * D;
        }
        const f4 v = ((const f4*)src)[lane];    // 512 B/symbol, L2-resident
        ((f4*)(out + off))[lane] = v;           // 512 B contiguous/symbol
    }
}

extern "C" void kernel_launch(void* const* d_in, const int* in_sizes, int n_in,
                              void* d_out, int out_size, void* d_ws, size_t ws_size,
                              hipStream_t stream) {
    const int*   idx_c = (const int*)  d_in[0];
    const int*   idx_f = (const int*)  d_in[1];
    const float* cb_c  = (const float*)d_in[2];
    const float* cb_f  = (const float*)d_in[3];
    const float* u_c   = (const float*)d_in[4];
    const float* u_f   = (const float*)d_in[5];
    float*       out   = (float*)d_out;
    (void)d_ws; (void)ws_size;

    fused_kernel<<<GRID, 256, 0, stream>>>(idx_c, idx_f, cb_c, cb_f, u_c, u_f, out);
}